// Round 1
// baseline (667.694 us; speedup 1.0000x reference)
//
#include <hip/hip_runtime.h>

#define NNODES 100000
#define NEDGES 1600000
#define INDIM 128
#define HID 32
#define HEADS 4
#define OUTDIM 64
#define NEG_SLOPE 0.2f

__device__ __forceinline__ float lrelu(float x) { return x > 0.f ? x : NEG_SLOPE * x; }

// ---------------- CSR build (dst-sorted) ----------------
__global__ void k_degree(const int* __restrict__ dst, int* __restrict__ deg, int E) {
    int i = blockIdx.x * blockDim.x + threadIdx.x;
    if (i < E) atomicAdd(&deg[dst[i]], 1);
}

__global__ void k_scanA(const int* __restrict__ deg, int* __restrict__ rowptr,
                        int* __restrict__ bsum, int N) {
    __shared__ int ls[1024];
    int t = threadIdx.x;
    int i = blockIdx.x * 1024 + t;
    int v = (i < N) ? deg[i] : 0;
    ls[t] = v;
    __syncthreads();
    for (int off = 1; off < 1024; off <<= 1) {
        int add = (t >= off) ? ls[t - off] : 0;
        __syncthreads();
        ls[t] += add;
        __syncthreads();
    }
    int incl = ls[t];
    if (i < N) rowptr[i] = incl - v;  // exclusive within block
    if (t == 1023) bsum[blockIdx.x] = incl;
}

__global__ void k_scanB(const int* __restrict__ bsum, int* __restrict__ boff, int nb) {
    __shared__ int ls[128];
    int t = threadIdx.x;
    int v = (t < nb) ? bsum[t] : 0;
    ls[t] = v;
    __syncthreads();
    for (int off = 1; off < 128; off <<= 1) {
        int add = (t >= off) ? ls[t - off] : 0;
        __syncthreads();
        ls[t] += add;
        __syncthreads();
    }
    if (t < nb) boff[t] = ls[t] - v;
}

__global__ void k_scanC(int* __restrict__ rowptr, int* __restrict__ cursor,
                        const int* __restrict__ boff, int N, int E) {
    int t = threadIdx.x;
    int i = blockIdx.x * 1024 + t;
    if (i < N) {
        int r = rowptr[i] + boff[blockIdx.x];
        rowptr[i] = r;
        cursor[i] = r;
    }
    if (blockIdx.x == 0 && t == 0) rowptr[N] = E;
}

__global__ void k_fill(const int* __restrict__ src, const int* __restrict__ dst,
                       int* __restrict__ cursor, int* __restrict__ csr_src, int E) {
    int i = blockIdx.x * blockDim.x + threadIdx.x;
    if (i < E) {
        int d = dst[i];
        int slot = atomicAdd(&cursor[d], 1);
        csr_src[slot] = src[i];
    }
}

// ---------------- GEMM 1: h1[N,128] = x[N,128] @ W1[128,128] + b1 ----------------
__global__ __launch_bounds__(256) void k_gemm1(const float* __restrict__ x,
                                               const float* __restrict__ W,
                                               const float* __restrict__ b,
                                               float* __restrict__ h) {
    __shared__ float Ws[INDIM * 128];  // 64KB
    int t = threadIdx.x;
    const float4* W4 = (const float4*)W;
    float4* Ws4 = (float4*)Ws;
    #pragma unroll
    for (int i = t; i < INDIM * 128 / 4; i += 256) Ws4[i] = W4[i];
    __syncthreads();

    int cg = t & 31;       // 32 col groups x 4 cols = 128 cols
    int rg = t >> 5;       // 8 row groups x 8 rows = 64 rows/block
    int r0 = blockIdx.x * 64 + rg * 8;
    const float4* x4 = (const float4*)x;

    int ridx[8];
    #pragma unroll
    for (int rr = 0; rr < 8; ++rr) {
        int r = r0 + rr;
        ridx[rr] = r < NNODES ? r : NNODES - 1;
    }
    float4 acc[8];
    #pragma unroll
    for (int rr = 0; rr < 8; ++rr) acc[rr] = make_float4(0.f, 0.f, 0.f, 0.f);

    for (int k = 0; k < INDIM; k += 4) {
        float4 wv0 = Ws4[(k + 0) * 32 + cg];
        float4 wv1 = Ws4[(k + 1) * 32 + cg];
        float4 wv2 = Ws4[(k + 2) * 32 + cg];
        float4 wv3 = Ws4[(k + 3) * 32 + cg];
        #pragma unroll
        for (int rr = 0; rr < 8; ++rr) {
            float4 xv = x4[(size_t)ridx[rr] * 32 + (k >> 2)];
            acc[rr].x = fmaf(xv.x, wv0.x, fmaf(xv.y, wv1.x, fmaf(xv.z, wv2.x, fmaf(xv.w, wv3.x, acc[rr].x))));
            acc[rr].y = fmaf(xv.x, wv0.y, fmaf(xv.y, wv1.y, fmaf(xv.z, wv2.y, fmaf(xv.w, wv3.y, acc[rr].y))));
            acc[rr].z = fmaf(xv.x, wv0.z, fmaf(xv.y, wv1.z, fmaf(xv.z, wv2.z, fmaf(xv.w, wv3.z, acc[rr].z))));
            acc[rr].w = fmaf(xv.x, wv0.w, fmaf(xv.y, wv1.w, fmaf(xv.z, wv2.w, fmaf(xv.w, wv3.w, acc[rr].w))));
        }
    }
    float4 bv = ((const float4*)b)[cg];
    #pragma unroll
    for (int rr = 0; rr < 8; ++rr) {
        int r = r0 + rr;
        if (r < NNODES) {
            float4 o;
            o.x = acc[rr].x + bv.x;
            o.y = acc[rr].y + bv.y;
            o.z = acc[rr].z + bv.z;
            o.w = acc[rr].w + bv.w;
            ((float4*)h)[(size_t)r * 32 + cg] = o;
        }
    }
}

// ---------------- GEMM 2: h2[N,64] = eluh[N,128] @ W2[128,64] + b2 ----------------
__global__ __launch_bounds__(256) void k_gemm2(const float* __restrict__ x,
                                               const float* __restrict__ W,
                                               const float* __restrict__ b,
                                               float* __restrict__ h) {
    __shared__ float Ws[128 * OUTDIM];  // 32KB
    int t = threadIdx.x;
    const float4* W4 = (const float4*)W;
    float4* Ws4 = (float4*)Ws;
    #pragma unroll
    for (int i = t; i < 128 * OUTDIM / 4; i += 256) Ws4[i] = W4[i];
    __syncthreads();

    int cg = t & 15;       // 16 col groups x 4 = 64 cols
    int rg = t >> 4;       // 16 row groups x 4 rows = 64 rows/block
    int r0 = blockIdx.x * 64 + rg * 4;
    const float4* x4 = (const float4*)x;

    int ridx[4];
    #pragma unroll
    for (int rr = 0; rr < 4; ++rr) {
        int r = r0 + rr;
        ridx[rr] = r < NNODES ? r : NNODES - 1;
    }
    float4 acc[4];
    #pragma unroll
    for (int rr = 0; rr < 4; ++rr) acc[rr] = make_float4(0.f, 0.f, 0.f, 0.f);

    for (int k = 0; k < 128; k += 4) {
        float4 wv0 = Ws4[(k + 0) * 16 + cg];
        float4 wv1 = Ws4[(k + 1) * 16 + cg];
        float4 wv2 = Ws4[(k + 2) * 16 + cg];
        float4 wv3 = Ws4[(k + 3) * 16 + cg];
        #pragma unroll
        for (int rr = 0; rr < 4; ++rr) {
            float4 xv = x4[(size_t)ridx[rr] * 32 + (k >> 2)];
            acc[rr].x = fmaf(xv.x, wv0.x, fmaf(xv.y, wv1.x, fmaf(xv.z, wv2.x, fmaf(xv.w, wv3.x, acc[rr].x))));
            acc[rr].y = fmaf(xv.x, wv0.y, fmaf(xv.y, wv1.y, fmaf(xv.z, wv2.y, fmaf(xv.w, wv3.y, acc[rr].y))));
            acc[rr].z = fmaf(xv.x, wv0.z, fmaf(xv.y, wv1.z, fmaf(xv.z, wv2.z, fmaf(xv.w, wv3.z, acc[rr].z))));
            acc[rr].w = fmaf(xv.x, wv0.w, fmaf(xv.y, wv1.w, fmaf(xv.z, wv2.w, fmaf(xv.w, wv3.w, acc[rr].w))));
        }
    }
    float4 bv = ((const float4*)b)[cg];
    #pragma unroll
    for (int rr = 0; rr < 4; ++rr) {
        int r = r0 + rr;
        if (r < NNODES) {
            float4 o;
            o.x = acc[rr].x + bv.x;
            o.y = acc[rr].y + bv.y;
            o.z = acc[rr].z + bv.z;
            o.w = acc[rr].w + bv.w;
            ((float4*)h)[(size_t)r * 16 + cg] = o;
        }
    }
}

// ---------------- alpha_src/alpha_dst, layer 1 (4 heads x 32) ----------------
__global__ void k_alpha1(const float* __restrict__ h, const float* __restrict__ a_src,
                         const float* __restrict__ a_dst, float* __restrict__ asrc,
                         float* __restrict__ adst) {
    int t = threadIdx.x;
    int n = blockIdx.x * 4 + (t >> 6);
    if (n >= NNODES) return;
    int l = t & 63;
    int c0 = 2 * l;
    int head = l >> 4;
    float2 hv = *(const float2*)&h[(size_t)n * 128 + c0];
    int wi = head * HID + (c0 & 31);
    float ps = hv.x * a_src[wi] + hv.y * a_src[wi + 1];
    float pd = hv.x * a_dst[wi] + hv.y * a_dst[wi + 1];
    #pragma unroll
    for (int off = 1; off < 16; off <<= 1) {
        ps += __shfl_xor(ps, off, 16);
        pd += __shfl_xor(pd, off, 16);
    }
    if ((l & 15) == 0) {
        asrc[n * 4 + head] = ps;
        adst[n * 4 + head] = pd;
    }
}

// ---------------- alpha, layer 2 (1 head x 64) ----------------
__global__ void k_alpha2(const float* __restrict__ h, const float* __restrict__ a_src,
                         const float* __restrict__ a_dst, float* __restrict__ asrc,
                         float* __restrict__ adst) {
    int t = threadIdx.x;
    int n = blockIdx.x * 4 + (t >> 6);
    if (n >= NNODES) return;
    int l = t & 63;
    float hv = h[(size_t)n * 64 + l];
    float ps = hv * a_src[l];
    float pd = hv * a_dst[l];
    #pragma unroll
    for (int off = 1; off < 64; off <<= 1) {
        ps += __shfl_xor(ps, off, 64);
        pd += __shfl_xor(pd, off, 64);
    }
    if (l == 0) {
        asrc[n] = ps;
        adst[n] = pd;
    }
}

// ---------------- aggregation layer 1: gather per dst node, fused softmax+ELU ----------------
__global__ __launch_bounds__(256) void k_agg1(const float* __restrict__ h,
                                              const float* __restrict__ asrc,
                                              const float* __restrict__ adst,
                                              const int* __restrict__ rowptr,
                                              const int* __restrict__ csr_src,
                                              const float* __restrict__ b,
                                              float* __restrict__ out) {
    int t = threadIdx.x;
    int n = blockIdx.x * 4 + (t >> 6);
    if (n >= NNODES) return;
    int l = t & 63;
    int head = l >> 4;
    int c0 = 2 * l;

    float adsth = adst[n * 4 + head];
    // self-loop term
    float w = __expf(lrelu(asrc[n * 4 + head] + adsth));
    float2 hv = *(const float2*)&h[(size_t)n * 128 + c0];
    float dsum = w;
    float a0 = w * hv.x;
    float a1 = w * hv.y;

    int beg = rowptr[n];
    int end = rowptr[n + 1];
    for (int p = beg; p < end; ++p) {
        int s = __builtin_amdgcn_readfirstlane(csr_src[p]);
        float ws = __expf(lrelu(asrc[(size_t)s * 4 + head] + adsth));
        float2 hs = *(const float2*)&h[(size_t)s * 128 + c0];
        dsum += ws;
        a0 = fmaf(ws, hs.x, a0);
        a1 = fmaf(ws, hs.y, a1);
    }
    float inv = 1.0f / dsum;
    float r0 = a0 * inv + b[c0];
    float r1 = a1 * inv + b[c0 + 1];
    // ELU
    r0 = r0 > 0.f ? r0 : __expf(r0) - 1.f;
    r1 = r1 > 0.f ? r1 : __expf(r1) - 1.f;
    *(float2*)&out[(size_t)n * 128 + c0] = make_float2(r0, r1);
}

// ---------------- aggregation layer 2: writes final output ----------------
__global__ __launch_bounds__(256) void k_agg2(const float* __restrict__ h,
                                              const float* __restrict__ asrc,
                                              const float* __restrict__ adst,
                                              const int* __restrict__ rowptr,
                                              const int* __restrict__ csr_src,
                                              const float* __restrict__ b,
                                              float* __restrict__ out) {
    int t = threadIdx.x;
    int n = blockIdx.x * 4 + (t >> 6);
    if (n >= NNODES) return;
    int l = t & 63;

    float adv = adst[n];
    float w = __expf(lrelu(asrc[n] + adv));
    float dsum = w;
    float acc = w * h[(size_t)n * 64 + l];

    int beg = rowptr[n];
    int end = rowptr[n + 1];
    for (int p = beg; p < end; ++p) {
        int s = __builtin_amdgcn_readfirstlane(csr_src[p]);
        float ws = __expf(lrelu(asrc[s] + adv));
        acc = fmaf(ws, h[(size_t)s * 64 + l], acc);
        dsum += ws;
    }
    out[(size_t)n * 64 + l] = acc / dsum + b[l];
}

extern "C" void kernel_launch(void* const* d_in, const int* in_sizes, int n_in,
                              void* d_out, int out_size, void* d_ws, size_t ws_size,
                              hipStream_t stream) {
    const float* x      = (const float*)d_in[0];
    const int*   ei     = (const int*)d_in[1];
    const float* W1     = (const float*)d_in[2];
    const float* a_src1 = (const float*)d_in[3];
    const float* a_dst1 = (const float*)d_in[4];
    const float* b1     = (const float*)d_in[5];
    const float* W2     = (const float*)d_in[6];
    const float* a_src2 = (const float*)d_in[7];
    const float* a_dst2 = (const float*)d_in[8];
    const float* b2     = (const float*)d_in[9];
    float* out = (float*)d_out;

    const int* src = ei;
    const int* dst = ei + NEDGES;

    char* ws = (char*)d_ws;
    size_t off = 0;
    auto alloc = [&](size_t bytes) {
        void* p = ws + off;
        off += (bytes + 255) & ~255ull;
        return p;
    };
    int* rowptr   = (int*)alloc((NNODES + 1) * sizeof(int));
    int* cursor   = (int*)alloc(NNODES * sizeof(int));
    int* csr_src  = (int*)alloc((size_t)NEDGES * sizeof(int));
    float* h1     = (float*)alloc((size_t)NNODES * 128 * sizeof(float));  // reused as h2
    float* eluh   = (float*)alloc((size_t)NNODES * 128 * sizeof(float));
    float* asrc1  = (float*)alloc((size_t)NNODES * 4 * sizeof(float));    // reused layer 2
    float* adst1  = (float*)alloc((size_t)NNODES * 4 * sizeof(float));    // reused layer 2
    int* bsum     = (int*)alloc(128 * sizeof(int));
    int* boff     = (int*)alloc(129 * sizeof(int));

    int nb = (NNODES + 1023) / 1024;  // 98

    hipMemsetAsync(cursor, 0, NNODES * sizeof(int), stream);
    k_degree<<<(NEDGES + 255) / 256, 256, 0, stream>>>(dst, cursor, NEDGES);
    k_scanA<<<nb, 1024, 0, stream>>>(cursor, rowptr, bsum, NNODES);
    k_scanB<<<1, 128, 0, stream>>>(bsum, boff, nb);
    k_scanC<<<nb, 1024, 0, stream>>>(rowptr, cursor, boff, NNODES, NEDGES);
    k_fill<<<(NEDGES + 255) / 256, 256, 0, stream>>>(src, dst, cursor, csr_src, NEDGES);

    // layer 1
    k_gemm1<<<(NNODES + 63) / 64, 256, 0, stream>>>(x, W1, b1, h1);
    k_alpha1<<<(NNODES + 3) / 4, 256, 0, stream>>>(h1, a_src1, a_dst1, asrc1, adst1);
    k_agg1<<<(NNODES + 3) / 4, 256, 0, stream>>>(h1, asrc1, adst1, rowptr, csr_src, b1, eluh);

    // layer 2 (h2 overlays h1; asrc/adst buffers reused)
    k_gemm2<<<(NNODES + 63) / 64, 256, 0, stream>>>(eluh, W2, b2, h1);
    k_alpha2<<<(NNODES + 3) / 4, 256, 0, stream>>>(h1, a_src2, a_dst2, asrc1, adst1);
    k_agg2<<<(NNODES + 3) / 4, 256, 0, stream>>>(h1, asrc1, adst1, rowptr, csr_src, b2, out);
}

// Round 7
// 547.705 us; speedup vs baseline: 1.2191x; 1.2191x over previous
//
// Round 7 resubmission: identical logic to round-4/5/6 source
// (round-1 structure + 4x-unrolled agg loops).
// Rounds 4-6 failed host-side ("No space left on device", now even when
// writing the .cpp itself) before any compile/GPU work — pure infra failure.
#include <hip/hip_runtime.h>

#define NNODES 100000
#define NEDGES 1600000
#define INDIM 128
#define HID 32
#define HEADS 4
#define OUTDIM 64
#define NEG_SLOPE 0.2f

__device__ __forceinline__ float lrelu(float x) { return x > 0.f ? x : NEG_SLOPE * x; }

// ---------------- CSR build (dst-sorted) ----------------
__global__ void k_degree(const int* __restrict__ dst, int* __restrict__ deg, int E) {
    int i = blockIdx.x * blockDim.x + threadIdx.x;
    if (i < E) atomicAdd(&deg[dst[i]], 1);
}

__global__ void k_scanA(const int* __restrict__ deg, int* __restrict__ rowptr,
                        int* __restrict__ bsum, int N) {
    __shared__ int ls[1024];
    int t = threadIdx.x;
    int i = blockIdx.x * 1024 + t;
    int v = (i < N) ? deg[i] : 0;
    ls[t] = v;
    __syncthreads();
    for (int off = 1; off < 1024; off <<= 1) {
        int add = (t >= off) ? ls[t - off] : 0;
        __syncthreads();
        ls[t] += add;
        __syncthreads();
    }
    int incl = ls[t];
    if (i < N) rowptr[i] = incl - v;  // exclusive within block
    if (t == 1023) bsum[blockIdx.x] = incl;
}

__global__ void k_scanB(const int* __restrict__ bsum, int* __restrict__ boff, int nb) {
    __shared__ int ls[128];
    int t = threadIdx.x;
    int v = (t < nb) ? bsum[t] : 0;
    ls[t] = v;
    __syncthreads();
    for (int off = 1; off < 128; off <<= 1) {
        int add = (t >= off) ? ls[t - off] : 0;
        __syncthreads();
        ls[t] += add;
        __syncthreads();
    }
    if (t < nb) boff[t] = ls[t] - v;
}

__global__ void k_scanC(int* __restrict__ rowptr, int* __restrict__ cursor,
                        const int* __restrict__ boff, int N, int E) {
    int t = threadIdx.x;
    int i = blockIdx.x * 1024 + t;
    if (i < N) {
        int r = rowptr[i] + boff[blockIdx.x];
        rowptr[i] = r;
        cursor[i] = r;
    }
    if (blockIdx.x == 0 && t == 0) rowptr[N] = E;
}

__global__ void k_fill(const int* __restrict__ src, const int* __restrict__ dst,
                       int* __restrict__ cursor, int* __restrict__ csr_src, int E) {
    int i = blockIdx.x * blockDim.x + threadIdx.x;
    if (i < E) {
        int d = dst[i];
        int slot = atomicAdd(&cursor[d], 1);
        csr_src[slot] = src[i];
    }
}

// ---------------- GEMM 1: h1[N,128] = x[N,128] @ W1[128,128] + b1 ----------------
__global__ __launch_bounds__(256) void k_gemm1(const float* __restrict__ x,
                                               const float* __restrict__ W,
                                               const float* __restrict__ b,
                                               float* __restrict__ h) {
    __shared__ float Ws[INDIM * 128];  // 64KB
    int t = threadIdx.x;
    const float4* W4 = (const float4*)W;
    float4* Ws4 = (float4*)Ws;
    #pragma unroll
    for (int i = t; i < INDIM * 128 / 4; i += 256) Ws4[i] = W4[i];
    __syncthreads();

    int cg = t & 31;       // 32 col groups x 4 cols = 128 cols
    int rg = t >> 5;       // 8 row groups x 8 rows = 64 rows/block
    int r0 = blockIdx.x * 64 + rg * 8;
    const float4* x4 = (const float4*)x;

    int ridx[8];
    #pragma unroll
    for (int rr = 0; rr < 8; ++rr) {
        int r = r0 + rr;
        ridx[rr] = r < NNODES ? r : NNODES - 1;
    }
    float4 acc[8];
    #pragma unroll
    for (int rr = 0; rr < 8; ++rr) acc[rr] = make_float4(0.f, 0.f, 0.f, 0.f);

    for (int k = 0; k < INDIM; k += 4) {
        float4 wv0 = Ws4[(k + 0) * 32 + cg];
        float4 wv1 = Ws4[(k + 1) * 32 + cg];
        float4 wv2 = Ws4[(k + 2) * 32 + cg];
        float4 wv3 = Ws4[(k + 3) * 32 + cg];
        #pragma unroll
        for (int rr = 0; rr < 8; ++rr) {
            float4 xv = x4[(size_t)ridx[rr] * 32 + (k >> 2)];
            acc[rr].x = fmaf(xv.x, wv0.x, fmaf(xv.y, wv1.x, fmaf(xv.z, wv2.x, fmaf(xv.w, wv3.x, acc[rr].x))));
            acc[rr].y = fmaf(xv.x, wv0.y, fmaf(xv.y, wv1.y, fmaf(xv.z, wv2.y, fmaf(xv.w, wv3.y, acc[rr].y))));
            acc[rr].z = fmaf(xv.x, wv0.z, fmaf(xv.y, wv1.z, fmaf(xv.z, wv2.z, fmaf(xv.w, wv3.z, acc[rr].z))));
            acc[rr].w = fmaf(xv.x, wv0.w, fmaf(xv.y, wv1.w, fmaf(xv.z, wv2.w, fmaf(xv.w, wv3.w, acc[rr].w))));
        }
    }
    float4 bv = ((const float4*)b)[cg];
    #pragma unroll
    for (int rr = 0; rr < 8; ++rr) {
        int r = r0 + rr;
        if (r < NNODES) {
            float4 o;
            o.x = acc[rr].x + bv.x;
            o.y = acc[rr].y + bv.y;
            o.z = acc[rr].z + bv.z;
            o.w = acc[rr].w + bv.w;
            ((float4*)h)[(size_t)r * 32 + cg] = o;
        }
    }
}

// ---------------- GEMM 2: h2[N,64] = eluh[N,128] @ W2[128,64] + b2 ----------------
__global__ __launch_bounds__(256) void k_gemm2(const float* __restrict__ x,
                                               const float* __restrict__ W,
                                               const float* __restrict__ b,
                                               float* __restrict__ h) {
    __shared__ float Ws[128 * OUTDIM];  // 32KB
    int t = threadIdx.x;
    const float4* W4 = (const float4*)W;
    float4* Ws4 = (float4*)Ws;
    #pragma unroll
    for (int i = t; i < 128 * OUTDIM / 4; i += 256) Ws4[i] = W4[i];
    __syncthreads();

    int cg = t & 15;       // 16 col groups x 4 = 64 cols
    int rg = t >> 4;       // 16 row groups x 4 rows = 64 rows/block
    int r0 = blockIdx.x * 64 + rg * 4;
    const float4* x4 = (const float4*)x;

    int ridx[4];
    #pragma unroll
    for (int rr = 0; rr < 4; ++rr) {
        int r = r0 + rr;
        ridx[rr] = r < NNODES ? r : NNODES - 1;
    }
    float4 acc[4];
    #pragma unroll
    for (int rr = 0; rr < 4; ++rr) acc[rr] = make_float4(0.f, 0.f, 0.f, 0.f);

    for (int k = 0; k < 128; k += 4) {
        float4 wv0 = Ws4[(k + 0) * 16 + cg];
        float4 wv1 = Ws4[(k + 1) * 16 + cg];
        float4 wv2 = Ws4[(k + 2) * 16 + cg];
        float4 wv3 = Ws4[(k + 3) * 16 + cg];
        #pragma unroll
        for (int rr = 0; rr < 4; ++rr) {
            float4 xv = x4[(size_t)ridx[rr] * 32 + (k >> 2)];
            acc[rr].x = fmaf(xv.x, wv0.x, fmaf(xv.y, wv1.x, fmaf(xv.z, wv2.x, fmaf(xv.w, wv3.x, acc[rr].x))));
            acc[rr].y = fmaf(xv.x, wv0.y, fmaf(xv.y, wv1.y, fmaf(xv.z, wv2.y, fmaf(xv.w, wv3.y, acc[rr].y))));
            acc[rr].z = fmaf(xv.x, wv0.z, fmaf(xv.y, wv1.z, fmaf(xv.z, wv2.z, fmaf(xv.w, wv3.z, acc[rr].z))));
            acc[rr].w = fmaf(xv.x, wv0.w, fmaf(xv.y, wv1.w, fmaf(xv.z, wv2.w, fmaf(xv.w, wv3.w, acc[rr].w))));
        }
    }
    float4 bv = ((const float4*)b)[cg];
    #pragma unroll
    for (int rr = 0; rr < 4; ++rr) {
        int r = r0 + rr;
        if (r < NNODES) {
            float4 o;
            o.x = acc[rr].x + bv.x;
            o.y = acc[rr].y + bv.y;
            o.z = acc[rr].z + bv.z;
            o.w = acc[rr].w + bv.w;
            ((float4*)h)[(size_t)r * 16 + cg] = o;
        }
    }
}

// ---------------- alpha_src/alpha_dst, layer 1 (4 heads x 32) ----------------
__global__ void k_alpha1(const float* __restrict__ h, const float* __restrict__ a_src,
                         const float* __restrict__ a_dst, float* __restrict__ asrc,
                         float* __restrict__ adst) {
    int t = threadIdx.x;
    int n = blockIdx.x * 4 + (t >> 6);
    if (n >= NNODES) return;
    int l = t & 63;
    int c0 = 2 * l;
    int head = l >> 4;
    float2 hv = *(const float2*)&h[(size_t)n * 128 + c0];
    int wi = head * HID + (c0 & 31);
    float ps = hv.x * a_src[wi] + hv.y * a_src[wi + 1];
    float pd = hv.x * a_dst[wi] + hv.y * a_dst[wi + 1];
    #pragma unroll
    for (int off = 1; off < 16; off <<= 1) {
        ps += __shfl_xor(ps, off, 16);
        pd += __shfl_xor(pd, off, 16);
    }
    if ((l & 15) == 0) {
        asrc[n * 4 + head] = ps;
        adst[n * 4 + head] = pd;
    }
}

// ---------------- alpha, layer 2 (1 head x 64) ----------------
__global__ void k_alpha2(const float* __restrict__ h, const float* __restrict__ a_src,
                         const float* __restrict__ a_dst, float* __restrict__ asrc,
                         float* __restrict__ adst) {
    int t = threadIdx.x;
    int n = blockIdx.x * 4 + (t >> 6);
    if (n >= NNODES) return;
    int l = t & 63;
    float hv = h[(size_t)n * 64 + l];
    float ps = hv * a_src[l];
    float pd = hv * a_dst[l];
    #pragma unroll
    for (int off = 1; off < 64; off <<= 1) {
        ps += __shfl_xor(ps, off, 64);
        pd += __shfl_xor(pd, off, 64);
    }
    if (l == 0) {
        asrc[n] = ps;
        adst[n] = pd;
    }
}

// ---------------- aggregation layer 1: gather per dst node, fused softmax+ELU ----------------
__global__ __launch_bounds__(256) void k_agg1(const float* __restrict__ h,
                                              const float* __restrict__ asrc,
                                              const float* __restrict__ adst,
                                              const int* __restrict__ rowptr,
                                              const int* __restrict__ csr_src,
                                              const float* __restrict__ b,
                                              float* __restrict__ out) {
    int t = threadIdx.x;
    int n = blockIdx.x * 4 + (t >> 6);
    if (n >= NNODES) return;
    int l = t & 63;
    int head = l >> 4;
    int c0 = 2 * l;

    float adsth = adst[n * 4 + head];
    // self-loop term
    float w = __expf(lrelu(asrc[n * 4 + head] + adsth));
    float2 hv = *(const float2*)&h[(size_t)n * 128 + c0];
    float dsum = w;
    float a0 = w * hv.x;
    float a1 = w * hv.y;

    int beg = rowptr[n];
    int end = rowptr[n + 1];
    int p = beg;
    for (; p + 4 <= end; p += 4) {
        int s0 = __builtin_amdgcn_readfirstlane(csr_src[p + 0]);
        int s1 = __builtin_amdgcn_readfirstlane(csr_src[p + 1]);
        int s2 = __builtin_amdgcn_readfirstlane(csr_src[p + 2]);
        int s3 = __builtin_amdgcn_readfirstlane(csr_src[p + 3]);
        float w0 = __expf(lrelu(asrc[(size_t)s0 * 4 + head] + adsth));
        float w1 = __expf(lrelu(asrc[(size_t)s1 * 4 + head] + adsth));
        float w2 = __expf(lrelu(asrc[(size_t)s2 * 4 + head] + adsth));
        float w3 = __expf(lrelu(asrc[(size_t)s3 * 4 + head] + adsth));
        float2 h0 = *(const float2*)&h[(size_t)s0 * 128 + c0];
        float2 h1 = *(const float2*)&h[(size_t)s1 * 128 + c0];
        float2 h2 = *(const float2*)&h[(size_t)s2 * 128 + c0];
        float2 h3 = *(const float2*)&h[(size_t)s3 * 128 + c0];
        dsum += (w0 + w1) + (w2 + w3);
        a0 = fmaf(w0, h0.x, a0); a1 = fmaf(w0, h0.y, a1);
        a0 = fmaf(w1, h1.x, a0); a1 = fmaf(w1, h1.y, a1);
        a0 = fmaf(w2, h2.x, a0); a1 = fmaf(w2, h2.y, a1);
        a0 = fmaf(w3, h3.x, a0); a1 = fmaf(w3, h3.y, a1);
    }
    for (; p < end; ++p) {
        int s = __builtin_amdgcn_readfirstlane(csr_src[p]);
        float ws = __expf(lrelu(asrc[(size_t)s * 4 + head] + adsth));
        float2 hs = *(const float2*)&h[(size_t)s * 128 + c0];
        dsum += ws;
        a0 = fmaf(ws, hs.x, a0);
        a1 = fmaf(ws, hs.y, a1);
    }
    float inv = 1.0f / dsum;
    float r0 = a0 * inv + b[c0];
    float r1 = a1 * inv + b[c0 + 1];
    // ELU
    r0 = r0 > 0.f ? r0 : __expf(r0) - 1.f;
    r1 = r1 > 0.f ? r1 : __expf(r1) - 1.f;
    *(float2*)&out[(size_t)n * 128 + c0] = make_float2(r0, r1);
}

// ---------------- aggregation layer 2: writes final output ----------------
__global__ __launch_bounds__(256) void k_agg2(const float* __restrict__ h,
                                              const float* __restrict__ asrc,
                                              const float* __restrict__ adst,
                                              const int* __restrict__ rowptr,
                                              const int* __restrict__ csr_src,
                                              const float* __restrict__ b,
                                              float* __restrict__ out) {
    int t = threadIdx.x;
    int n = blockIdx.x * 4 + (t >> 6);
    if (n >= NNODES) return;
    int l = t & 63;

    float adv = adst[n];
    float w = __expf(lrelu(asrc[n] + adv));
    float dsum = w;
    float acc = w * h[(size_t)n * 64 + l];

    int beg = rowptr[n];
    int end = rowptr[n + 1];
    int p = beg;
    for (; p + 4 <= end; p += 4) {
        int s0 = __builtin_amdgcn_readfirstlane(csr_src[p + 0]);
        int s1 = __builtin_amdgcn_readfirstlane(csr_src[p + 1]);
        int s2 = __builtin_amdgcn_readfirstlane(csr_src[p + 2]);
        int s3 = __builtin_amdgcn_readfirstlane(csr_src[p + 3]);
        float w0 = __expf(lrelu(asrc[s0] + adv));
        float w1 = __expf(lrelu(asrc[s1] + adv));
        float w2 = __expf(lrelu(asrc[s2] + adv));
        float w3 = __expf(lrelu(asrc[s3] + adv));
        float h0 = h[(size_t)s0 * 64 + l];
        float h1 = h[(size_t)s1 * 64 + l];
        float h2 = h[(size_t)s2 * 64 + l];
        float h3 = h[(size_t)s3 * 64 + l];
        dsum += (w0 + w1) + (w2 + w3);
        acc = fmaf(w0, h0, acc);
        acc = fmaf(w1, h1, acc);
        acc = fmaf(w2, h2, acc);
        acc = fmaf(w3, h3, acc);
    }
    for (; p < end; ++p) {
        int s = __builtin_amdgcn_readfirstlane(csr_src[p]);
        float ws = __expf(lrelu(asrc[s] + adv));
        acc = fmaf(ws, h[(size_t)s * 64 + l], acc);
        dsum += ws;
    }
    out[(size_t)n * 64 + l] = acc / dsum + b[l];
}

extern "C" void kernel_launch(void* const* d_in, const int* in_sizes, int n_in,
                              void* d_out, int out_size, void* d_ws, size_t ws_size,
                              hipStream_t stream) {
    const float* x      = (const float*)d_in[0];
    const int*   ei     = (const int*)d_in[1];
    const float* W1     = (const float*)d_in[2];
    const float* a_src1 = (const float*)d_in[3];
    const float* a_dst1 = (const float*)d_in[4];
    const float* b1     = (const float*)d_in[5];
    const float* W2     = (const float*)d_in[6];
    const float* a_src2 = (const float*)d_in[7];
    const float* a_dst2 = (const float*)d_in[8];
    const float* b2     = (const float*)d_in[9];
    float* out = (float*)d_out;

    const int* src = ei;
    const int* dst = ei + NEDGES;

    char* ws = (char*)d_ws;
    size_t off = 0;
    auto alloc = [&](size_t bytes) {
        void* p = ws + off;
        off += (bytes + 255) & ~255ull;
        return p;
    };
    int* rowptr   = (int*)alloc((NNODES + 1) * sizeof(int));
    int* cursor   = (int*)alloc(NNODES * sizeof(int));
    int* csr_src  = (int*)alloc((size_t)NEDGES * sizeof(int));
    float* h1     = (float*)alloc((size_t)NNODES * 128 * sizeof(float));  // reused as h2
    float* eluh   = (float*)alloc((size_t)NNODES * 128 * sizeof(float));
    float* asrc1  = (float*)alloc((size_t)NNODES * 4 * sizeof(float));    // reused layer 2
    float* adst1  = (float*)alloc((size_t)NNODES * 4 * sizeof(float));    // reused layer 2
    int* bsum     = (int*)alloc(128 * sizeof(int));
    int* boff     = (int*)alloc(129 * sizeof(int));

    int nb = (NNODES + 1023) / 1024;  // 98

    hipMemsetAsync(cursor, 0, NNODES * sizeof(int), stream);
    k_degree<<<(NEDGES + 255) / 256, 256, 0, stream>>>(dst, cursor, NEDGES);
    k_scanA<<<nb, 1024, 0, stream>>>(cursor, rowptr, bsum, NNODES);
    k_scanB<<<1, 128, 0, stream>>>(bsum, boff, nb);
    k_scanC<<<nb, 1024, 0, stream>>>(rowptr, cursor, boff, NNODES, NEDGES);
    k_fill<<<(NEDGES + 255) / 256, 256, 0, stream>>>(src, dst, cursor, csr_src, NEDGES);

    // layer 1
    k_gemm1<<<(NNODES + 63) / 64, 256, 0, stream>>>(x, W1, b1, h1);
    k_alpha1<<<(NNODES + 3) / 4, 256, 0, stream>>>(h1, a_src1, a_dst1, asrc1, adst1);
    k_agg1<<<(NNODES + 3) / 4, 256, 0, stream>>>(h1, asrc1, adst1, rowptr, csr_src, b1, eluh);

    // layer 2 (h2 overlays h1; asrc/adst buffers reused)
    k_gemm2<<<(NNODES + 63) / 64, 256, 0, stream>>>(eluh, W2, b2, h1);
    k_alpha2<<<(NNODES + 3) / 4, 256, 0, stream>>>(h1, a_src2, a_dst2, asrc1, adst1);
    k_agg2<<<(NNODES + 3) / 4, 256, 0, stream>>>(h1, asrc1, adst1, rowptr, csr_src, b2, out);
}

// Round 9
// 480.529 us; speedup vs baseline: 1.3895x; 1.1398x over previous
//
// Round 9: round-7 proven base + ONE change: h stored fp16 for aggregation
// (halves gather bytes; h1 fits better in L2/L3). Alpha kernels kept separate
// (round-7 structure) and adapted to fp16 h. Workspace ~87 MB.
#include <hip/hip_runtime.h>
#include <hip/hip_fp16.h>

#define NNODES 100000
#define NEDGES 1600000
#define INDIM 128
#define HID 32
#define HEADS 4
#define OUTDIM 64
#define NEG_SLOPE 0.2f

__device__ __forceinline__ float lrelu(float x) { return x > 0.f ? x : NEG_SLOPE * x; }

// ---------------- CSR build (dst-sorted) ----------------
__global__ void k_degree(const int* __restrict__ dst, int* __restrict__ deg, int E) {
    int i = blockIdx.x * blockDim.x + threadIdx.x;
    if (i < E) atomicAdd(&deg[dst[i]], 1);
}

__global__ void k_scanA(const int* __restrict__ deg, int* __restrict__ rowptr,
                        int* __restrict__ bsum, int N) {
    __shared__ int ls[1024];
    int t = threadIdx.x;
    int i = blockIdx.x * 1024 + t;
    int v = (i < N) ? deg[i] : 0;
    ls[t] = v;
    __syncthreads();
    for (int off = 1; off < 1024; off <<= 1) {
        int add = (t >= off) ? ls[t - off] : 0;
        __syncthreads();
        ls[t] += add;
        __syncthreads();
    }
    int incl = ls[t];
    if (i < N) rowptr[i] = incl - v;  // exclusive within block
    if (t == 1023) bsum[blockIdx.x] = incl;
}

__global__ void k_scanB(const int* __restrict__ bsum, int* __restrict__ boff, int nb) {
    __shared__ int ls[128];
    int t = threadIdx.x;
    int v = (t < nb) ? bsum[t] : 0;
    ls[t] = v;
    __syncthreads();
    for (int off = 1; off < 128; off <<= 1) {
        int add = (t >= off) ? ls[t - off] : 0;
        __syncthreads();
        ls[t] += add;
        __syncthreads();
    }
    if (t < nb) boff[t] = ls[t] - v;
}

__global__ void k_scanC(int* __restrict__ rowptr, int* __restrict__ cursor,
                        const int* __restrict__ boff, int N, int E) {
    int t = threadIdx.x;
    int i = blockIdx.x * 1024 + t;
    if (i < N) {
        int r = rowptr[i] + boff[blockIdx.x];
        rowptr[i] = r;
        cursor[i] = r;
    }
    if (blockIdx.x == 0 && t == 0) rowptr[N] = E;
}

__global__ void k_fill(const int* __restrict__ src, const int* __restrict__ dst,
                       int* __restrict__ cursor, int* __restrict__ csr_src, int E) {
    int i = blockIdx.x * blockDim.x + threadIdx.x;
    if (i < E) {
        int d = dst[i];
        int slot = atomicAdd(&cursor[d], 1);
        csr_src[slot] = src[i];
    }
}

// ---------------- GEMM 1: h1h[N,128](fp16) = x @ W1 ----------------
__global__ __launch_bounds__(256) void k_gemm1(const float* __restrict__ x,
                                               const float* __restrict__ W,
                                               __half* __restrict__ h) {
    __shared__ float Ws[INDIM * 128];  // 64KB
    int t = threadIdx.x;
    const float4* W4 = (const float4*)W;
    float4* Ws4 = (float4*)Ws;
    #pragma unroll
    for (int i = t; i < INDIM * 128 / 4; i += 256) Ws4[i] = W4[i];
    __syncthreads();

    int cg = t & 31;       // 32 col groups x 4 cols = 128 cols
    int rg = t >> 5;       // 8 row groups x 8 rows = 64 rows/block
    int r0 = blockIdx.x * 64 + rg * 8;
    const float4* x4 = (const float4*)x;

    int ridx[8];
    #pragma unroll
    for (int rr = 0; rr < 8; ++rr) {
        int r = r0 + rr;
        ridx[rr] = r < NNODES ? r : NNODES - 1;
    }
    float4 acc[8];
    #pragma unroll
    for (int rr = 0; rr < 8; ++rr) acc[rr] = make_float4(0.f, 0.f, 0.f, 0.f);

    for (int k = 0; k < INDIM; k += 4) {
        float4 wv0 = Ws4[(k + 0) * 32 + cg];
        float4 wv1 = Ws4[(k + 1) * 32 + cg];
        float4 wv2 = Ws4[(k + 2) * 32 + cg];
        float4 wv3 = Ws4[(k + 3) * 32 + cg];
        #pragma unroll
        for (int rr = 0; rr < 8; ++rr) {
            float4 xv = x4[(size_t)ridx[rr] * 32 + (k >> 2)];
            acc[rr].x = fmaf(xv.x, wv0.x, fmaf(xv.y, wv1.x, fmaf(xv.z, wv2.x, fmaf(xv.w, wv3.x, acc[rr].x))));
            acc[rr].y = fmaf(xv.x, wv0.y, fmaf(xv.y, wv1.y, fmaf(xv.z, wv2.y, fmaf(xv.w, wv3.y, acc[rr].y))));
            acc[rr].z = fmaf(xv.x, wv0.z, fmaf(xv.y, wv1.z, fmaf(xv.z, wv2.z, fmaf(xv.w, wv3.z, acc[rr].z))));
            acc[rr].w = fmaf(xv.x, wv0.w, fmaf(xv.y, wv1.w, fmaf(xv.z, wv2.w, fmaf(xv.w, wv3.w, acc[rr].w))));
        }
    }
    #pragma unroll
    for (int rr = 0; rr < 8; ++rr) {
        int r = r0 + rr;
        if (r < NNODES) {
            union { __half2 h2[2]; uint2 u; } pk;
            pk.h2[0] = __floats2half2_rn(acc[rr].x, acc[rr].y);
            pk.h2[1] = __floats2half2_rn(acc[rr].z, acc[rr].w);
            ((uint2*)h)[(size_t)r * 32 + cg] = pk.u;
        }
    }
}

// ---------------- GEMM 2: h2h[N,64](fp16) = eluh @ W2 ----------------
__global__ __launch_bounds__(256) void k_gemm2(const float* __restrict__ x,
                                               const float* __restrict__ W,
                                               __half* __restrict__ h) {
    __shared__ float Ws[128 * OUTDIM];  // 32KB
    int t = threadIdx.x;
    const float4* W4 = (const float4*)W;
    float4* Ws4 = (float4*)Ws;
    #pragma unroll
    for (int i = t; i < 128 * OUTDIM / 4; i += 256) Ws4[i] = W4[i];
    __syncthreads();

    int cg = t & 15;       // 16 col groups x 4 = 64 cols
    int rg = t >> 4;       // 16 row groups x 4 rows = 64 rows/block
    int r0 = blockIdx.x * 64 + rg * 4;
    const float4* x4 = (const float4*)x;

    int ridx[4];
    #pragma unroll
    for (int rr = 0; rr < 4; ++rr) {
        int r = r0 + rr;
        ridx[rr] = r < NNODES ? r : NNODES - 1;
    }
    float4 acc[4];
    #pragma unroll
    for (int rr = 0; rr < 4; ++rr) acc[rr] = make_float4(0.f, 0.f, 0.f, 0.f);

    for (int k = 0; k < 128; k += 4) {
        float4 wv0 = Ws4[(k + 0) * 16 + cg];
        float4 wv1 = Ws4[(k + 1) * 16 + cg];
        float4 wv2 = Ws4[(k + 2) * 16 + cg];
        float4 wv3 = Ws4[(k + 3) * 16 + cg];
        #pragma unroll
        for (int rr = 0; rr < 4; ++rr) {
            float4 xv = x4[(size_t)ridx[rr] * 32 + (k >> 2)];
            acc[rr].x = fmaf(xv.x, wv0.x, fmaf(xv.y, wv1.x, fmaf(xv.z, wv2.x, fmaf(xv.w, wv3.x, acc[rr].x))));
            acc[rr].y = fmaf(xv.x, wv0.y, fmaf(xv.y, wv1.y, fmaf(xv.z, wv2.y, fmaf(xv.w, wv3.y, acc[rr].y))));
            acc[rr].z = fmaf(xv.x, wv0.z, fmaf(xv.y, wv1.z, fmaf(xv.z, wv2.z, fmaf(xv.w, wv3.z, acc[rr].z))));
            acc[rr].w = fmaf(xv.x, wv0.w, fmaf(xv.y, wv1.w, fmaf(xv.z, wv2.w, fmaf(xv.w, wv3.w, acc[rr].w))));
        }
    }
    #pragma unroll
    for (int rr = 0; rr < 4; ++rr) {
        int r = r0 + rr;
        if (r < NNODES) {
            union { __half2 h2[2]; uint2 u; } pk;
            pk.h2[0] = __floats2half2_rn(acc[rr].x, acc[rr].y);
            pk.h2[1] = __floats2half2_rn(acc[rr].z, acc[rr].w);
            ((uint2*)h)[(size_t)r * 16 + cg] = pk.u;
        }
    }
}

// ---------------- alpha_src/alpha_dst, layer 1 (4 heads x 32), fp16 h ----------------
__global__ void k_alpha1(const __half* __restrict__ h, const float* __restrict__ a_src,
                         const float* __restrict__ a_dst, float* __restrict__ asrc,
                         float* __restrict__ adst) {
    int t = threadIdx.x;
    int n = blockIdx.x * 4 + (t >> 6);
    if (n >= NNODES) return;
    int l = t & 63;
    int c0 = 2 * l;
    int head = l >> 4;
    float2 hv = __half22float2(((const __half2*)h)[(size_t)n * 64 + l]);
    int wi = head * HID + (c0 & 31);
    float ps = hv.x * a_src[wi] + hv.y * a_src[wi + 1];
    float pd = hv.x * a_dst[wi] + hv.y * a_dst[wi + 1];
    #pragma unroll
    for (int off = 1; off < 16; off <<= 1) {
        ps += __shfl_xor(ps, off, 16);
        pd += __shfl_xor(pd, off, 16);
    }
    if ((l & 15) == 0) {
        asrc[n * 4 + head] = ps;
        adst[n * 4 + head] = pd;
    }
}

// ---------------- alpha, layer 2 (1 head x 64), fp16 h ----------------
__global__ void k_alpha2(const __half* __restrict__ h, const float* __restrict__ a_src,
                         const float* __restrict__ a_dst, float* __restrict__ asrc,
                         float* __restrict__ adst) {
    int t = threadIdx.x;
    int n = blockIdx.x * 4 + (t >> 6);
    if (n >= NNODES) return;
    int l = t & 63;
    float hv = __half2float(h[(size_t)n * 64 + l]);
    float ps = hv * a_src[l];
    float pd = hv * a_dst[l];
    #pragma unroll
    for (int off = 1; off < 64; off <<= 1) {
        ps += __shfl_xor(ps, off, 64);
        pd += __shfl_xor(pd, off, 64);
    }
    if (l == 0) {
        asrc[n] = ps;
        adst[n] = pd;
    }
}

// ---------------- aggregation layer 1: fp16 h gathers, fused softmax+ELU ----------------
__global__ __launch_bounds__(256) void k_agg1(const __half* __restrict__ h,
                                              const float* __restrict__ asrc,
                                              const float* __restrict__ adst,
                                              const int* __restrict__ rowptr,
                                              const int* __restrict__ csr_src,
                                              const float* __restrict__ b,
                                              float* __restrict__ out) {
    int t = threadIdx.x;
    int n = blockIdx.x * 4 + (t >> 6);
    if (n >= NNODES) return;
    int l = t & 63;
    int head = l >> 4;
    int c0 = 2 * l;
    const __half2* hh = (const __half2*)h;

    float adsth = adst[n * 4 + head];
    // self-loop term
    float w = __expf(lrelu(asrc[n * 4 + head] + adsth));
    float2 hv = __half22float2(hh[(size_t)n * 64 + l]);
    float dsum = w;
    float a0 = w * hv.x;
    float a1 = w * hv.y;

    int beg = rowptr[n];
    int end = rowptr[n + 1];
    int p = beg;
    for (; p + 4 <= end; p += 4) {
        int s0 = __builtin_amdgcn_readfirstlane(csr_src[p + 0]);
        int s1 = __builtin_amdgcn_readfirstlane(csr_src[p + 1]);
        int s2 = __builtin_amdgcn_readfirstlane(csr_src[p + 2]);
        int s3 = __builtin_amdgcn_readfirstlane(csr_src[p + 3]);
        float w0 = __expf(lrelu(asrc[(size_t)s0 * 4 + head] + adsth));
        float w1 = __expf(lrelu(asrc[(size_t)s1 * 4 + head] + adsth));
        float w2 = __expf(lrelu(asrc[(size_t)s2 * 4 + head] + adsth));
        float w3 = __expf(lrelu(asrc[(size_t)s3 * 4 + head] + adsth));
        float2 h0 = __half22float2(hh[(size_t)s0 * 64 + l]);
        float2 h1 = __half22float2(hh[(size_t)s1 * 64 + l]);
        float2 h2 = __half22float2(hh[(size_t)s2 * 64 + l]);
        float2 h3 = __half22float2(hh[(size_t)s3 * 64 + l]);
        dsum += (w0 + w1) + (w2 + w3);
        a0 = fmaf(w0, h0.x, a0); a1 = fmaf(w0, h0.y, a1);
        a0 = fmaf(w1, h1.x, a0); a1 = fmaf(w1, h1.y, a1);
        a0 = fmaf(w2, h2.x, a0); a1 = fmaf(w2, h2.y, a1);
        a0 = fmaf(w3, h3.x, a0); a1 = fmaf(w3, h3.y, a1);
    }
    for (; p < end; ++p) {
        int s = __builtin_amdgcn_readfirstlane(csr_src[p]);
        float ws = __expf(lrelu(asrc[(size_t)s * 4 + head] + adsth));
        float2 hs = __half22float2(hh[(size_t)s * 64 + l]);
        dsum += ws;
        a0 = fmaf(ws, hs.x, a0);
        a1 = fmaf(ws, hs.y, a1);
    }
    float inv = 1.0f / dsum;
    float r0 = a0 * inv + b[c0];
    float r1 = a1 * inv + b[c0 + 1];
    // ELU
    r0 = r0 > 0.f ? r0 : __expf(r0) - 1.f;
    r1 = r1 > 0.f ? r1 : __expf(r1) - 1.f;
    *(float2*)&out[(size_t)n * 128 + c0] = make_float2(r0, r1);
}

// ---------------- aggregation layer 2: fp16 h gathers, writes final output ----------------
__global__ __launch_bounds__(256) void k_agg2(const __half* __restrict__ h,
                                              const float* __restrict__ asrc,
                                              const float* __restrict__ adst,
                                              const int* __restrict__ rowptr,
                                              const int* __restrict__ csr_src,
                                              const float* __restrict__ b,
                                              float* __restrict__ out) {
    int t = threadIdx.x;
    int n = blockIdx.x * 4 + (t >> 6);
    if (n >= NNODES) return;
    int l = t & 63;

    float adv = adst[n];
    float w = __expf(lrelu(asrc[n] + adv));
    float dsum = w;
    float acc = w * __half2float(h[(size_t)n * 64 + l]);

    int beg = rowptr[n];
    int end = rowptr[n + 1];
    int p = beg;
    for (; p + 4 <= end; p += 4) {
        int s0 = __builtin_amdgcn_readfirstlane(csr_src[p + 0]);
        int s1 = __builtin_amdgcn_readfirstlane(csr_src[p + 1]);
        int s2 = __builtin_amdgcn_readfirstlane(csr_src[p + 2]);
        int s3 = __builtin_amdgcn_readfirstlane(csr_src[p + 3]);
        float w0 = __expf(lrelu(asrc[s0] + adv));
        float w1 = __expf(lrelu(asrc[s1] + adv));
        float w2 = __expf(lrelu(asrc[s2] + adv));
        float w3 = __expf(lrelu(asrc[s3] + adv));
        float h0 = __half2float(h[(size_t)s0 * 64 + l]);
        float h1 = __half2float(h[(size_t)s1 * 64 + l]);
        float h2 = __half2float(h[(size_t)s2 * 64 + l]);
        float h3 = __half2float(h[(size_t)s3 * 64 + l]);
        dsum += (w0 + w1) + (w2 + w3);
        acc = fmaf(w0, h0, acc);
        acc = fmaf(w1, h1, acc);
        acc = fmaf(w2, h2, acc);
        acc = fmaf(w3, h3, acc);
    }
    for (; p < end; ++p) {
        int s = __builtin_amdgcn_readfirstlane(csr_src[p]);
        float ws = __expf(lrelu(asrc[s] + adv));
        acc = fmaf(ws, __half2float(h[(size_t)s * 64 + l]), acc);
        dsum += ws;
    }
    out[(size_t)n * 64 + l] = acc / dsum + b[l];
}

extern "C" void kernel_launch(void* const* d_in, const int* in_sizes, int n_in,
                              void* d_out, int out_size, void* d_ws, size_t ws_size,
                              hipStream_t stream) {
    const float* x      = (const float*)d_in[0];
    const int*   ei     = (const int*)d_in[1];
    const float* W1     = (const float*)d_in[2];
    const float* a_src1 = (const float*)d_in[3];
    const float* a_dst1 = (const float*)d_in[4];
    const float* b1     = (const float*)d_in[5];
    const float* W2     = (const float*)d_in[6];
    const float* a_src2 = (const float*)d_in[7];
    const float* a_dst2 = (const float*)d_in[8];
    const float* b2     = (const float*)d_in[9];
    float* out = (float*)d_out;

    const int* src = ei;
    const int* dst = ei + NEDGES;

    char* ws = (char*)d_ws;
    size_t off = 0;
    auto alloc = [&](size_t bytes) {
        void* p = ws + off;
        off += (bytes + 255) & ~255ull;
        return p;
    };
    int* rowptr   = (int*)alloc((NNODES + 1) * sizeof(int));
    int* cursor   = (int*)alloc(NNODES * sizeof(int));
    int* csr_src  = (int*)alloc((size_t)NEDGES * sizeof(int));
    __half* h1h   = (__half*)alloc((size_t)NNODES * 128 * sizeof(__half)); // 25.6MB; layer-2 h overlays
    float* eluh   = (float*)alloc((size_t)NNODES * 128 * sizeof(float));   // 51.2MB
    float* asrc1  = (float*)alloc((size_t)NNODES * 4 * sizeof(float));     // reused layer 2
    float* adst1  = (float*)alloc((size_t)NNODES * 4 * sizeof(float));     // reused layer 2
    int* bsum     = (int*)alloc(128 * sizeof(int));
    int* boff     = (int*)alloc(129 * sizeof(int));

    int nb = (NNODES + 1023) / 1024;  // 98

    hipMemsetAsync(cursor, 0, NNODES * sizeof(int), stream);
    k_degree<<<(NEDGES + 255) / 256, 256, 0, stream>>>(dst, cursor, NEDGES);
    k_scanA<<<nb, 1024, 0, stream>>>(cursor, rowptr, bsum, NNODES);
    k_scanB<<<1, 128, 0, stream>>>(bsum, boff, nb);
    k_scanC<<<nb, 1024, 0, stream>>>(rowptr, cursor, boff, NNODES, NEDGES);
    k_fill<<<(NEDGES + 255) / 256, 256, 0, stream>>>(src, dst, cursor, csr_src, NEDGES);

    int gn = (NNODES + 3) / 4;

    // layer 1
    k_gemm1<<<(NNODES + 63) / 64, 256, 0, stream>>>(x, W1, h1h);
    k_alpha1<<<gn, 256, 0, stream>>>(h1h, a_src1, a_dst1, asrc1, adst1);
    k_agg1<<<gn, 256, 0, stream>>>(h1h, asrc1, adst1, rowptr, csr_src, b1, eluh);

    // layer 2 (h overlays h1h; asrc/adst reused)
    k_gemm2<<<(NNODES + 63) / 64, 256, 0, stream>>>(eluh, W2, h1h);
    k_alpha2<<<gn, 256, 0, stream>>>(h1h, a_src2, a_dst2, asrc1, adst1);
    k_agg2<<<gn, 256, 0, stream>>>(h1h, asrc1, adst1, rowptr, csr_src, b2, out);
}

// Round 10
// 437.425 us; speedup vs baseline: 1.5264x; 1.0985x over previous
//
// Round 10: (a) dst-range-partitioned, XCD-affine CSR fill — kills the 16x
// write amplification seen in round 9 (WRITE_SIZE 106MB for 6.4MB payload);
// (b) agg loops unrolled 8x (VGPR=12, free MLP). Base: round-9 (fp16 h).
#include <hip/hip_runtime.h>
#include <hip/hip_fp16.h>

#define NNODES 100000
#define NEDGES 1600000
#define INDIM 128
#define HID 32
#define HEADS 4
#define OUTDIM 64
#define NEG_SLOPE 0.2f
#define NRANGES 8
#define RSIZE (NNODES / NRANGES)  // 12500

__device__ __forceinline__ float lrelu(float x) { return x > 0.f ? x : NEG_SLOPE * x; }

// ---------------- CSR build (dst-sorted) ----------------
__global__ void k_degree(const int* __restrict__ dst, int* __restrict__ deg, int E) {
    int i = blockIdx.x * blockDim.x + threadIdx.x;
    if (i < E) atomicAdd(&deg[dst[i]], 1);
}

__global__ void k_scanA(const int* __restrict__ deg, int* __restrict__ rowptr,
                        int* __restrict__ bsum, int N) {
    __shared__ int ls[1024];
    int t = threadIdx.x;
    int i = blockIdx.x * 1024 + t;
    int v = (i < N) ? deg[i] : 0;
    ls[t] = v;
    __syncthreads();
    for (int off = 1; off < 1024; off <<= 1) {
        int add = (t >= off) ? ls[t - off] : 0;
        __syncthreads();
        ls[t] += add;
        __syncthreads();
    }
    int incl = ls[t];
    if (i < N) rowptr[i] = incl - v;  // exclusive within block
    if (t == 1023) bsum[blockIdx.x] = incl;
}

__global__ void k_scanB(const int* __restrict__ bsum, int* __restrict__ boff, int nb) {
    __shared__ int ls[128];
    int t = threadIdx.x;
    int v = (t < nb) ? bsum[t] : 0;
    ls[t] = v;
    __syncthreads();
    for (int off = 1; off < 128; off <<= 1) {
        int add = (t >= off) ? ls[t - off] : 0;
        __syncthreads();
        ls[t] += add;
        __syncthreads();
    }
    if (t < nb) boff[t] = ls[t] - v;
}

__global__ void k_scanC(int* __restrict__ rowptr, int* __restrict__ cursor,
                        const int* __restrict__ boff, int N, int E) {
    int t = threadIdx.x;
    int i = blockIdx.x * 1024 + t;
    if (i < N) {
        int r = rowptr[i] + boff[blockIdx.x];
        rowptr[i] = r;
        cursor[i] = r;
    }
    if (blockIdx.x == 0 && t == 0) rowptr[N] = E;
}

// dst-range partitioned fill: range = blockIdx & 7 (round-robins across the
// 8 XCDs per the dispatch heuristic), so each range's csr region is written
// from one XCD's L2 -> full-line writebacks instead of 16x amplification.
// Performance heuristic only; correct under any block->XCD mapping.
__global__ __launch_bounds__(256) void k_fill(const int* __restrict__ src,
                                              const int* __restrict__ dst,
                                              int* __restrict__ cursor,
                                              int* __restrict__ csr_src, int E) {
    int range = blockIdx.x & (NRANGES - 1);
    int chunk = blockIdx.x >> 3;
    int nchunks = gridDim.x >> 3;
    int lo = range * RSIZE;
    int hi = (range == NRANGES - 1) ? NNODES : lo + RSIZE;
    // contiguous per-chunk window keeps the 8 re-reads L2/line friendly
    int per = (E + nchunks - 1) / nchunks;
    int beg = chunk * per;
    int end = min(E, beg + per);
    for (int i = beg + threadIdx.x; i < end; i += 256) {
        int d = dst[i];
        if (d >= lo && d < hi) {
            int slot = atomicAdd(&cursor[d], 1);
            csr_src[slot] = src[i];
        }
    }
}

// ---------------- GEMM 1: h1h[N,128](fp16) = x @ W1 ----------------
__global__ __launch_bounds__(256) void k_gemm1(const float* __restrict__ x,
                                               const float* __restrict__ W,
                                               __half* __restrict__ h) {
    __shared__ float Ws[INDIM * 128];  // 64KB
    int t = threadIdx.x;
    const float4* W4 = (const float4*)W;
    float4* Ws4 = (float4*)Ws;
    #pragma unroll
    for (int i = t; i < INDIM * 128 / 4; i += 256) Ws4[i] = W4[i];
    __syncthreads();

    int cg = t & 31;
    int rg = t >> 5;
    int r0 = blockIdx.x * 64 + rg * 8;
    const float4* x4 = (const float4*)x;

    int ridx[8];
    #pragma unroll
    for (int rr = 0; rr < 8; ++rr) {
        int r = r0 + rr;
        ridx[rr] = r < NNODES ? r : NNODES - 1;
    }
    float4 acc[8];
    #pragma unroll
    for (int rr = 0; rr < 8; ++rr) acc[rr] = make_float4(0.f, 0.f, 0.f, 0.f);

    for (int k = 0; k < INDIM; k += 4) {
        float4 wv0 = Ws4[(k + 0) * 32 + cg];
        float4 wv1 = Ws4[(k + 1) * 32 + cg];
        float4 wv2 = Ws4[(k + 2) * 32 + cg];
        float4 wv3 = Ws4[(k + 3) * 32 + cg];
        #pragma unroll
        for (int rr = 0; rr < 8; ++rr) {
            float4 xv = x4[(size_t)ridx[rr] * 32 + (k >> 2)];
            acc[rr].x = fmaf(xv.x, wv0.x, fmaf(xv.y, wv1.x, fmaf(xv.z, wv2.x, fmaf(xv.w, wv3.x, acc[rr].x))));
            acc[rr].y = fmaf(xv.x, wv0.y, fmaf(xv.y, wv1.y, fmaf(xv.z, wv2.y, fmaf(xv.w, wv3.y, acc[rr].y))));
            acc[rr].z = fmaf(xv.x, wv0.z, fmaf(xv.y, wv1.z, fmaf(xv.z, wv2.z, fmaf(xv.w, wv3.z, acc[rr].z))));
            acc[rr].w = fmaf(xv.x, wv0.w, fmaf(xv.y, wv1.w, fmaf(xv.z, wv2.w, fmaf(xv.w, wv3.w, acc[rr].w))));
        }
    }
    #pragma unroll
    for (int rr = 0; rr < 8; ++rr) {
        int r = r0 + rr;
        if (r < NNODES) {
            union { __half2 h2[2]; uint2 u; } pk;
            pk.h2[0] = __floats2half2_rn(acc[rr].x, acc[rr].y);
            pk.h2[1] = __floats2half2_rn(acc[rr].z, acc[rr].w);
            ((uint2*)h)[(size_t)r * 32 + cg] = pk.u;
        }
    }
}

// ---------------- GEMM 2: h2h[N,64](fp16) = eluh @ W2 ----------------
__global__ __launch_bounds__(256) void k_gemm2(const float* __restrict__ x,
                                               const float* __restrict__ W,
                                               __half* __restrict__ h) {
    __shared__ float Ws[128 * OUTDIM];  // 32KB
    int t = threadIdx.x;
    const float4* W4 = (const float4*)W;
    float4* Ws4 = (float4*)Ws;
    #pragma unroll
    for (int i = t; i < 128 * OUTDIM / 4; i += 256) Ws4[i] = W4[i];
    __syncthreads();

    int cg = t & 15;
    int rg = t >> 4;
    int r0 = blockIdx.x * 64 + rg * 4;
    const float4* x4 = (const float4*)x;

    int ridx[4];
    #pragma unroll
    for (int rr = 0; rr < 4; ++rr) {
        int r = r0 + rr;
        ridx[rr] = r < NNODES ? r : NNODES - 1;
    }
    float4 acc[4];
    #pragma unroll
    for (int rr = 0; rr < 4; ++rr) acc[rr] = make_float4(0.f, 0.f, 0.f, 0.f);

    for (int k = 0; k < 128; k += 4) {
        float4 wv0 = Ws4[(k + 0) * 16 + cg];
        float4 wv1 = Ws4[(k + 1) * 16 + cg];
        float4 wv2 = Ws4[(k + 2) * 16 + cg];
        float4 wv3 = Ws4[(k + 3) * 16 + cg];
        #pragma unroll
        for (int rr = 0; rr < 4; ++rr) {
            float4 xv = x4[(size_t)ridx[rr] * 32 + (k >> 2)];
            acc[rr].x = fmaf(xv.x, wv0.x, fmaf(xv.y, wv1.x, fmaf(xv.z, wv2.x, fmaf(xv.w, wv3.x, acc[rr].x))));
            acc[rr].y = fmaf(xv.x, wv0.y, fmaf(xv.y, wv1.y, fmaf(xv.z, wv2.y, fmaf(xv.w, wv3.y, acc[rr].y))));
            acc[rr].z = fmaf(xv.x, wv0.z, fmaf(xv.y, wv1.z, fmaf(xv.z, wv2.z, fmaf(xv.w, wv3.z, acc[rr].z))));
            acc[rr].w = fmaf(xv.x, wv0.w, fmaf(xv.y, wv1.w, fmaf(xv.z, wv2.w, fmaf(xv.w, wv3.w, acc[rr].w))));
        }
    }
    #pragma unroll
    for (int rr = 0; rr < 4; ++rr) {
        int r = r0 + rr;
        if (r < NNODES) {
            union { __half2 h2[2]; uint2 u; } pk;
            pk.h2[0] = __floats2half2_rn(acc[rr].x, acc[rr].y);
            pk.h2[1] = __floats2half2_rn(acc[rr].z, acc[rr].w);
            ((uint2*)h)[(size_t)r * 16 + cg] = pk.u;
        }
    }
}

// ---------------- alpha_src/alpha_dst, layer 1 (4 heads x 32), fp16 h ----------------
__global__ void k_alpha1(const __half* __restrict__ h, const float* __restrict__ a_src,
                         const float* __restrict__ a_dst, float* __restrict__ asrc,
                         float* __restrict__ adst) {
    int t = threadIdx.x;
    int n = blockIdx.x * 4 + (t >> 6);
    if (n >= NNODES) return;
    int l = t & 63;
    int c0 = 2 * l;
    int head = l >> 4;
    float2 hv = __half22float2(((const __half2*)h)[(size_t)n * 64 + l]);
    int wi = head * HID + (c0 & 31);
    float ps = hv.x * a_src[wi] + hv.y * a_src[wi + 1];
    float pd = hv.x * a_dst[wi] + hv.y * a_dst[wi + 1];
    #pragma unroll
    for (int off = 1; off < 16; off <<= 1) {
        ps += __shfl_xor(ps, off, 16);
        pd += __shfl_xor(pd, off, 16);
    }
    if ((l & 15) == 0) {
        asrc[n * 4 + head] = ps;
        adst[n * 4 + head] = pd;
    }
}

// ---------------- alpha, layer 2 (1 head x 64), fp16 h ----------------
__global__ void k_alpha2(const __half* __restrict__ h, const float* __restrict__ a_src,
                         const float* __restrict__ a_dst, float* __restrict__ asrc,
                         float* __restrict__ adst) {
    int t = threadIdx.x;
    int n = blockIdx.x * 4 + (t >> 6);
    if (n >= NNODES) return;
    int l = t & 63;
    float hv = __half2float(h[(size_t)n * 64 + l]);
    float ps = hv * a_src[l];
    float pd = hv * a_dst[l];
    #pragma unroll
    for (int off = 1; off < 64; off <<= 1) {
        ps += __shfl_xor(ps, off, 64);
        pd += __shfl_xor(pd, off, 64);
    }
    if (l == 0) {
        asrc[n] = ps;
        adst[n] = pd;
    }
}

// ---------------- aggregation layer 1: fp16 gathers, 8x unroll ----------------
__global__ __launch_bounds__(256) void k_agg1(const __half* __restrict__ h,
                                              const float* __restrict__ asrc,
                                              const float* __restrict__ adst,
                                              const int* __restrict__ rowptr,
                                              const int* __restrict__ csr_src,
                                              const float* __restrict__ b,
                                              float* __restrict__ out) {
    int t = threadIdx.x;
    int n = blockIdx.x * 4 + (t >> 6);
    if (n >= NNODES) return;
    int l = t & 63;
    int head = l >> 4;
    int c0 = 2 * l;
    const __half2* hh = (const __half2*)h;

    float adsth = adst[n * 4 + head];
    float w = __expf(lrelu(asrc[n * 4 + head] + adsth));
    float2 hv = __half22float2(hh[(size_t)n * 64 + l]);
    float dsum = w;
    float a0 = w * hv.x;
    float a1 = w * hv.y;

    int beg = rowptr[n];
    int end = rowptr[n + 1];
    int p = beg;
    for (; p + 8 <= end; p += 8) {
        int s[8];
        #pragma unroll
        for (int j = 0; j < 8; ++j) s[j] = __builtin_amdgcn_readfirstlane(csr_src[p + j]);
        float ww[8];
        #pragma unroll
        for (int j = 0; j < 8; ++j) ww[j] = __expf(lrelu(asrc[(size_t)s[j] * 4 + head] + adsth));
        float2 hx[8];
        #pragma unroll
        for (int j = 0; j < 8; ++j) hx[j] = __half22float2(hh[(size_t)s[j] * 64 + l]);
        #pragma unroll
        for (int j = 0; j < 8; ++j) {
            dsum += ww[j];
            a0 = fmaf(ww[j], hx[j].x, a0);
            a1 = fmaf(ww[j], hx[j].y, a1);
        }
    }
    for (; p < end; ++p) {
        int s = __builtin_amdgcn_readfirstlane(csr_src[p]);
        float ws = __expf(lrelu(asrc[(size_t)s * 4 + head] + adsth));
        float2 hs = __half22float2(hh[(size_t)s * 64 + l]);
        dsum += ws;
        a0 = fmaf(ws, hs.x, a0);
        a1 = fmaf(ws, hs.y, a1);
    }
    float inv = 1.0f / dsum;
    float r0 = a0 * inv + b[c0];
    float r1 = a1 * inv + b[c0 + 1];
    r0 = r0 > 0.f ? r0 : __expf(r0) - 1.f;
    r1 = r1 > 0.f ? r1 : __expf(r1) - 1.f;
    *(float2*)&out[(size_t)n * 128 + c0] = make_float2(r0, r1);
}

// ---------------- aggregation layer 2: fp16 gathers, 8x unroll ----------------
__global__ __launch_bounds__(256) void k_agg2(const __half* __restrict__ h,
                                              const float* __restrict__ asrc,
                                              const float* __restrict__ adst,
                                              const int* __restrict__ rowptr,
                                              const int* __restrict__ csr_src,
                                              const float* __restrict__ b,
                                              float* __restrict__ out) {
    int t = threadIdx.x;
    int n = blockIdx.x * 4 + (t >> 6);
    if (n >= NNODES) return;
    int l = t & 63;

    float adv = adst[n];
    float w = __expf(lrelu(asrc[n] + adv));
    float dsum = w;
    float acc = w * __half2float(h[(size_t)n * 64 + l]);

    int beg = rowptr[n];
    int end = rowptr[n + 1];
    int p = beg;
    for (; p + 8 <= end; p += 8) {
        int s[8];
        #pragma unroll
        for (int j = 0; j < 8; ++j) s[j] = __builtin_amdgcn_readfirstlane(csr_src[p + j]);
        float ww[8];
        #pragma unroll
        for (int j = 0; j < 8; ++j) ww[j] = __expf(lrelu(asrc[s[j]] + adv));
        float hx[8];
        #pragma unroll
        for (int j = 0; j < 8; ++j) hx[j] = __half2float(h[(size_t)s[j] * 64 + l]);
        #pragma unroll
        for (int j = 0; j < 8; ++j) {
            dsum += ww[j];
            acc = fmaf(ww[j], hx[j], acc);
        }
    }
    for (; p < end; ++p) {
        int s = __builtin_amdgcn_readfirstlane(csr_src[p]);
        float ws = __expf(lrelu(asrc[s] + adv));
        acc = fmaf(ws, __half2float(h[(size_t)s * 64 + l]), acc);
        dsum += ws;
    }
    out[(size_t)n * 64 + l] = acc / dsum + b[l];
}

extern "C" void kernel_launch(void* const* d_in, const int* in_sizes, int n_in,
                              void* d_out, int out_size, void* d_ws, size_t ws_size,
                              hipStream_t stream) {
    const float* x      = (const float*)d_in[0];
    const int*   ei     = (const int*)d_in[1];
    const float* W1     = (const float*)d_in[2];
    const float* a_src1 = (const float*)d_in[3];
    const float* a_dst1 = (const float*)d_in[4];
    const float* b1     = (const float*)d_in[5];
    const float* W2     = (const float*)d_in[6];
    const float* a_src2 = (const float*)d_in[7];
    const float* a_dst2 = (const float*)d_in[8];
    const float* b2     = (const float*)d_in[9];
    float* out = (float*)d_out;

    const int* src = ei;
    const int* dst = ei + NEDGES;

    char* ws = (char*)d_ws;
    size_t off = 0;
    auto alloc = [&](size_t bytes) {
        void* p = ws + off;
        off += (bytes + 255) & ~255ull;
        return p;
    };
    int* rowptr   = (int*)alloc((NNODES + 1) * sizeof(int));
    int* cursor   = (int*)alloc(NNODES * sizeof(int));
    int* csr_src  = (int*)alloc((size_t)NEDGES * sizeof(int));
    __half* h1h   = (__half*)alloc((size_t)NNODES * 128 * sizeof(__half)); // 25.6MB; layer-2 h overlays
    float* eluh   = (float*)alloc((size_t)NNODES * 128 * sizeof(float));   // 51.2MB
    float* asrc1  = (float*)alloc((size_t)NNODES * 4 * sizeof(float));     // reused layer 2
    float* adst1  = (float*)alloc((size_t)NNODES * 4 * sizeof(float));     // reused layer 2
    int* bsum     = (int*)alloc(128 * sizeof(int));
    int* boff     = (int*)alloc(129 * sizeof(int));

    int nb = (NNODES + 1023) / 1024;  // 98

    hipMemsetAsync(cursor, 0, NNODES * sizeof(int), stream);
    k_degree<<<(NEDGES + 255) / 256, 256, 0, stream>>>(dst, cursor, NEDGES);
    k_scanA<<<nb, 1024, 0, stream>>>(cursor, rowptr, bsum, NNODES);
    k_scanB<<<1, 128, 0, stream>>>(bsum, boff, nb);
    k_scanC<<<nb, 1024, 0, stream>>>(rowptr, cursor, boff, NNODES, NEDGES);
    // ranged, XCD-affine fill: 8 ranges x 200 chunks = 1600 blocks
    k_fill<<<NRANGES * 200, 256, 0, stream>>>(src, dst, cursor, csr_src, NEDGES);

    int gn = (NNODES + 3) / 4;

    // layer 1
    k_gemm1<<<(NNODES + 63) / 64, 256, 0, stream>>>(x, W1, h1h);
    k_alpha1<<<gn, 256, 0, stream>>>(h1h, a_src1, a_dst1, asrc1, adst1);
    k_agg1<<<gn, 256, 0, stream>>>(h1h, asrc1, adst1, rowptr, csr_src, b1, eluh);

    // layer 2 (h overlays h1h; asrc/adst reused)
    k_gemm2<<<(NNODES + 63) / 64, 256, 0, stream>>>(eluh, W2, h1h);
    k_alpha2<<<gn, 256, 0, stream>>>(h1h, a_src2, a_dst2, asrc1, adst1);
    k_agg2<<<gn, 256, 0, stream>>>(h1h, asrc1, adst1, rowptr, csr_src, b2, out);
}